// Round 12
// baseline (325.694 us; speedup 1.0000x reference)
//
#include <hip/hip_runtime.h>

// ---------------- problem constants ----------------
#define D_MODEL 1024
#define D_STATE 16
#define D_CONV  4
#define D_INNER 2048
#define DT_RANK 16
#define BATCH   2
#define SEQ     1024
#define M_ROWS  (BATCH*SEQ)   // 2048 rows
#define CHUNK   32            // timesteps per scan chunk
#define NCHUNK  (SEQ/CHUNK)   // 32 chunks
#define XP_KSPLIT 16
#define XP_KLEN (D_INNER / XP_KSPLIT)   // 128

typedef __bf16 bf16x8 __attribute__((ext_vector_type(8)));
typedef float  f32x4  __attribute__((ext_vector_type(4)));

__device__ __forceinline__ unsigned short f2bf(float f) {
  unsigned u = __float_as_uint(f);
  u += 0x7fffu + ((u >> 16) & 1u);      // round-to-nearest-even
  return (unsigned short)(u >> 16);
}

__device__ __forceinline__ float sigmoid_fast(float v) {
  return 1.f / (1.f + __expf(-v));
}

__device__ __forceinline__ float softplus_f(float s) {
  return (s > 20.f) ? s : __logf(1.f + __expf(s));
}

// async global->LDS, 16B per lane; LDS dest is wave-uniform base + lane*16 [m97/m104]
__device__ __forceinline__ void gll16(const void* g, void* l) {
  __builtin_amdgcn_global_load_lds(
      (const __attribute__((address_space(1))) unsigned int*)g,
      (__attribute__((address_space(3))) unsigned int*)l, 16, 0, 0);
}

// epilogue store helpers (f32 or bf16 C)
__device__ __forceinline__ void storeC(float v, float* p)          { *p = v; }
__device__ __forceinline__ void storeC(float v, unsigned short* p) { *p = f2bf(v); }

// ---------------- cast f32 -> bf16 + zero dlt/Bm/Cm/cnt ----------------
__global__ __launch_bounds__(256) void cast_all_kernel(
    const float* __restrict__ x, const float* __restrict__ w1, const float* __restrict__ w2,
    const float* __restrict__ xpw,
    unsigned short* __restrict__ xbf, unsigned short* __restrict__ w1bf,
    unsigned short* __restrict__ w2bf, unsigned short* __restrict__ xpwbf,
    float* __restrict__ zbuf /* dlt base; dlt|Bm|Cm|cnt contiguous */) {
  const int N0 = (M_ROWS * D_MODEL) / 4;        // 524288 float4
  const int N1 = (2 * D_INNER * D_MODEL) / 4;   // 1048576
  const int N2 = (D_MODEL * D_INNER) / 4;       // 524288
  const int N3 = (48 * D_INNER) / 4;            // 24576
  const int NZ = (3 * M_ROWS * 16 * 4 + 256) / 16;  // 24592 float4 (dlt|Bm|Cm|cnt)
  int i = blockIdx.x * 256 + threadIdx.x;       // grid = 8385 blocks
  const float* src; unsigned short* dst; int off;
  if (i < N0)                 { src = x;   dst = xbf;   off = i; }
  else if (i < N0 + N1)       { src = w1;  dst = w1bf;  off = i - N0; }
  else if (i < N0 + N1 + N2)  { src = w2;  dst = w2bf;  off = i - N0 - N1; }
  else if (i < N0 + N1 + N2 + N3) { src = xpw; dst = xpwbf; off = i - N0 - N1 - N2; }
  else {
    int zi = i - N0 - N1 - N2 - N3;
    if (zi < NZ) { float4 z = {0.f,0.f,0.f,0.f}; ((float4*)zbuf)[zi] = z; }
    return;
  }
  float4 v = *(const float4*)(src + (size_t)off * 4);
  ushort4 o;
  o.x = f2bf(v.x); o.y = f2bf(v.y); o.z = f2bf(v.z); o.w = f2bf(v.w);
  *(ushort4*)(dst + (size_t)off * 4) = o;
}

// ---------------- bf16 MFMA GEMM with global_load_lds staging (m97 structure) ----------
template<int BM, int BK, typename CT>
__global__ __launch_bounds__(256) void gemm_gll(
    const __bf16* __restrict__ A, const __bf16* __restrict__ B,
    const float* __restrict__ bias, CT* __restrict__ C,
    int M, int N, int K) {
  constexpr int MR  = BM / 32;
  constexpr int LPR = BK / 8;          // lanes per LDS row
  constexpr int RPI = 64 / LPR;        // rows per gll16 wave-instr
  __shared__ __bf16 As[BM][BK];
  __shared__ __bf16 Bs[128][BK];
  const int tid  = threadIdx.x;
  const int lane = tid & 63;
  const int w    = tid >> 6;
  const int wr   = w >> 1, wc = w & 1;
  const int rowBase = blockIdx.y * BM;
  const int colBase = blockIdx.x * 128;

  f32x4 acc[MR][4];
  #pragma unroll
  for (int i = 0; i < MR; ++i)
    #pragma unroll
    for (int j = 0; j < 4; ++j) { f32x4 z = {0.f,0.f,0.f,0.f}; acc[i][j] = z; }

  const int srow = lane / LPR;
  const int sk   = (lane % LPR) * 8;
  const int fr   = lane & 15;
  const int fk   = (lane >> 4) * 8;

  for (int k0 = 0; k0 < K; k0 += BK) {
    #pragma unroll
    for (int i = 0; i < BM / RPI / 4; ++i) {
      const int r0 = w * (BM / 4) + i * RPI;
      gll16(A + (size_t)(rowBase + r0 + srow) * K + k0 + sk, &As[r0][0]);
    }
    #pragma unroll
    for (int i = 0; i < 128 / RPI / 4; ++i) {
      const int r0 = w * 32 + i * RPI;
      gll16(B + (size_t)(colBase + r0 + srow) * K + k0 + sk, &Bs[r0][0]);
    }
    __syncthreads();

    #pragma unroll
    for (int kk = 0; kk < BK / 32; ++kk) {
      bf16x8 af[MR], bfr[4];
      #pragma unroll
      for (int mm = 0; mm < MR; ++mm)
        af[mm] = *(const bf16x8*)&As[wr * (BM / 2) + mm * 16 + fr][kk * 32 + fk];
      #pragma unroll
      for (int nn = 0; nn < 4; ++nn)
        bfr[nn] = *(const bf16x8*)&Bs[wc * 64 + nn * 16 + fr][kk * 32 + fk];
      #pragma unroll
      for (int mm = 0; mm < MR; ++mm)
        #pragma unroll
        for (int nn = 0; nn < 4; ++nn)
          acc[mm][nn] = __builtin_amdgcn_mfma_f32_16x16x32_bf16(af[mm], bfr[nn], acc[mm][nn], 0, 0, 0);
    }
    __syncthreads();
  }

  #pragma unroll
  for (int nn = 0; nn < 4; ++nn) {
    int col = colBase + wc * 64 + nn * 16 + fr;
    float bv = bias[col];
    #pragma unroll
    for (int mm = 0; mm < MR; ++mm) {
      int row0 = rowBase + wr * (BM / 2) + mm * 16 + (lane >> 4) * 4;
      #pragma unroll
      for (int r = 0; r < 4; ++r)
        storeC(acc[mm][nn][r] + bv, &C[(size_t)(row0 + r) * N + col]);
    }
  }
}

// ---------------- FUSED conv+SiLU + x_proj K-split MFMA ----------------
// grid (32 rowtiles x 64 rows, 16 ksplits x 128 d), 256 thr.
// Block: conv+silu its (row,d) slice (regs) -> write xsbf + stash in LDS As;
// stage xpw slice (gll16) -> 4x BK=32 MFMA -> atomicAdd partials to dlt/Bm/Cm.
__global__ __launch_bounds__(256) void convxproj_kernel(
    const unsigned short* __restrict__ xar, const float* __restrict__ cw,
    const float* __restrict__ cb, const __bf16* __restrict__ B,
    const float* __restrict__ xpb, unsigned short* __restrict__ xsbf,
    float* __restrict__ dlt, float* __restrict__ Bm, float* __restrict__ Cm) {
  __shared__ __bf16 As[64][128];   // 16 KB
  __shared__ __bf16 Bs[48][128];   // 12 KB
  const int tid  = threadIdx.x;
  const int lane = tid & 63;
  const int w    = tid >> 6;
  const int r0   = blockIdx.x * 64;
  const int k0   = blockIdx.y * XP_KLEN;
  const __bf16* xarb = (const __bf16*)xar;

  // ---- stage xpw slice: 48 rows x 128 d; 3 gll16 per wave (4 rows each) ----
  {
    const int srow = lane >> 4;          // 0..3
    const int sk   = (lane & 15) * 8;    // 0..120
    #pragma unroll
    for (int i = 0; i < 3; ++i) {
      const int rb = w * 12 + i * 4;
      gll16(B + (size_t)(rb + srow) * D_INNER + k0 + sk, &Bs[rb][0]);
    }
  }

  // ---- conv + silu for 64 rows x 128 d (4 chunks of 8 per thread) ----
  const int dc = (tid & 15) * 8;         // same for all p (256 % 16 == 0)
  const int d  = k0 + dc;
  float4 cwl[8];
  const float4* cw4 = (const float4*)cw;
  #pragma unroll
  for (int e = 0; e < 8; ++e) cwl[e] = cw4[d + e];
  float cbl[8];
  #pragma unroll
  for (int e = 0; e < 8; ++e) cbl[e] = cb[d + e];

  #pragma unroll
  for (int p = 0; p < 4; ++p) {
    int ch  = tid + p * 256;             // 0..1023
    int row = ch >> 4;                   // 0..63
    int m   = r0 + row;
    int t   = m & (SEQ - 1);
    float acc[8];
    #pragma unroll
    for (int e = 0; e < 8; ++e) acc[e] = cbl[e];
    #pragma unroll
    for (int j = 0; j < 4; ++j) {
      int tt = t - 3 + j;
      if (tt < 0) continue;              // causal zero-pad per batch
      bf16x8 v = *(const bf16x8*)&xarb[(size_t)(m - 3 + j) * (2 * D_INNER) + d];
      const float* cj = (const float*)cwl;
      #pragma unroll
      for (int e = 0; e < 8; ++e)
        acc[e] += (float)v[e] * cj[e * 4 + j];
    }
    unsigned short o[8];
    #pragma unroll
    for (int e = 0; e < 8; ++e) {
      float s = acc[e] * sigmoid_fast(acc[e]);
      o[e] = f2bf(s);
    }
    *(bf16x8*)&As[row][dc] = *(bf16x8*)&o[0];                         // LDS stash
    *(ushort4*)&xsbf[(size_t)m * D_INNER + d]     = *(ushort4*)&o[0]; // global
    *(ushort4*)&xsbf[(size_t)m * D_INNER + d + 4] = *(ushort4*)&o[4];
  }
  __syncthreads();   // drains gll16 + orders As writes

  // ---- MFMA: wave w owns rows w*16..w*16+15; 1x3 fragments; 4 BK=32 steps ----
  f32x4 acc3[3];
  #pragma unroll
  for (int j = 0; j < 3; ++j) { f32x4 z = {0.f,0.f,0.f,0.f}; acc3[j] = z; }
  const int fr = lane & 15;
  const int fk = (lane >> 4) * 8;
  #pragma unroll
  for (int kk = 0; kk < 4; ++kk) {
    bf16x8 af = *(const bf16x8*)&As[w * 16 + fr][kk * 32 + fk];
    #pragma unroll
    for (int nn = 0; nn < 3; ++nn) {
      bf16x8 bv = *(const bf16x8*)&Bs[nn * 16 + fr][kk * 32 + fk];
      acc3[nn] = __builtin_amdgcn_mfma_f32_16x16x32_bf16(af, bv, acc3[nn], 0, 0, 0);
    }
  }

  // C/D layout: col = lane&15, row = (lane>>4)*4 + reg. Bias only from ksplit 0.
  const float biasOn = (blockIdx.y == 0) ? 1.f : 0.f;
  #pragma unroll
  for (int nn = 0; nn < 3; ++nn) {
    float bv = biasOn * xpb[nn * 16 + fr];
    float* dst = (nn == 0) ? dlt : (nn == 1) ? Bm : Cm;
    int row0 = r0 + w * 16 + (lane >> 4) * 4;
    #pragma unroll
    for (int r = 0; r < 4; ++r)
      atomicAdd(&dst[(size_t)(row0 + r) * 16 + fr], acc3[nn][r] + bv);
  }
}

// ======================= chunked parallel selective scan =======================
// Phase1 (+fused phase2 tail): per-chunk local scan -> Hbuf/Sbuf; the LAST chunk
// block of each (b, 256-d column) (atomic counter) rewrites Hbuf in place with
// the TRUE h at chunk start. Phase3: replay; fuse y, D-skip, gate, bf16 cast.

#define DELTA16(sarr, ttq)                                                       \
  {                                                                              \
    float4 q0 = *(const float4*)&sarr[ttq][0];                                   \
    float4 q1 = *(const float4*)&sarr[ttq][4];                                   \
    float4 q2 = *(const float4*)&sarr[ttq][8];                                   \
    float4 q3 = *(const float4*)&sarr[ttq][12];                                  \
    s += q0.x*dtwr[0] + q0.y*dtwr[1] + q0.z*dtwr[2] + q0.w*dtwr[3];              \
    s += q1.x*dtwr[4] + q1.y*dtwr[5] + q1.z*dtwr[6] + q1.w*dtwr[7];              \
    s += q2.x*dtwr[8] + q2.y*dtwr[9] + q2.z*dtwr[10] + q2.w*dtwr[11];            \
    s += q3.x*dtwr[12] + q3.y*dtwr[13] + q3.z*dtwr[14] + q3.w*dtwr[15];          \
  }

__global__ __launch_bounds__(256) void scan_phase1(
    const unsigned short* __restrict__ xsbf, const float* __restrict__ dlt,
    const float* __restrict__ Bmat, const float* __restrict__ dtw,
    const float* __restrict__ dtb, const float* __restrict__ alog,
    float* __restrict__ Hbuf, float* __restrict__ Sbuf, int* __restrict__ cnt) {
  __shared__ float dltS[CHUNK][16];
  __shared__ float BS[CHUNK][16];
  __shared__ int lastFlag;
  const int tid = threadIdx.x;
  const int c   = blockIdx.y;
  const int b   = blockIdx.z;
  const int d   = blockIdx.x * 256 + tid;
  const int row0 = b * SEQ + c * CHUNK;
  const __bf16* xsb16 = (const __bf16*)xsbf;
  {
    int e = tid * 2;
    int tt = e >> 4, r = e & 15;
    *(float2*)&dltS[tt][r] = *(const float2*)&dlt[(row0 + tt) * 16 + r];
    *(float2*)&BS[tt][r]   = *(const float2*)&Bmat[(row0 + tt) * 16 + r];
  }
  float dtwr[16], An[16];
  #pragma unroll
  for (int q = 0; q < 4; ++q) {
    float4 w4 = *(const float4*)&dtw[d * 16 + q * 4];
    dtwr[q*4+0] = w4.x; dtwr[q*4+1] = w4.y; dtwr[q*4+2] = w4.z; dtwr[q*4+3] = w4.w;
    float4 a4 = *(const float4*)&alog[d * 16 + q * 4];
    An[q*4+0] = -__expf(a4.x); An[q*4+1] = -__expf(a4.y);
    An[q*4+2] = -__expf(a4.z); An[q*4+3] = -__expf(a4.w);
  }
  const float dtbv = dtb[d];
  float xv[CHUNK];
  #pragma unroll
  for (int tt = 0; tt < CHUNK; ++tt)
    xv[tt] = (float)xsb16[(size_t)(row0 + tt) * D_INNER + d];
  __syncthreads();
  float dv[CHUNK];
  #pragma unroll
  for (int tt = 0; tt < CHUNK; ++tt) {
    float s = dtbv;
    DELTA16(dltS, tt);
    dv[tt] = softplus_f(s);
  }
  float h[16];
  #pragma unroll
  for (int n = 0; n < 16; ++n) h[n] = 0.f;
  float Ssum = 0.f;
  #pragma unroll
  for (int tt = 0; tt < CHUNK; ++tt) {
    const float dvt = dv[tt];
    Ssum += dvt;
    const float dvx = dvt * xv[tt];
    float4 B0 = *(const float4*)&BS[tt][0];
    float4 B1 = *(const float4*)&BS[tt][4];
    float4 B2 = *(const float4*)&BS[tt][8];
    float4 B3 = *(const float4*)&BS[tt][12];
    h[0]  = __expf(dvt*An[0])*h[0]   + dvx*B0.x;
    h[1]  = __expf(dvt*An[1])*h[1]   + dvx*B0.y;
    h[2]  = __expf(dvt*An[2])*h[2]   + dvx*B0.z;
    h[3]  = __expf(dvt*An[3])*h[3]   + dvx*B0.w;
    h[4]  = __expf(dvt*An[4])*h[4]   + dvx*B1.x;
    h[5]  = __expf(dvt*An[5])*h[5]   + dvx*B1.y;
    h[6]  = __expf(dvt*An[6])*h[6]   + dvx*B1.z;
    h[7]  = __expf(dvt*An[7])*h[7]   + dvx*B1.w;
    h[8]  = __expf(dvt*An[8])*h[8]   + dvx*B2.x;
    h[9]  = __expf(dvt*An[9])*h[9]   + dvx*B2.y;
    h[10] = __expf(dvt*An[10])*h[10] + dvx*B2.z;
    h[11] = __expf(dvt*An[11])*h[11] + dvx*B2.w;
    h[12] = __expf(dvt*An[12])*h[12] + dvx*B3.x;
    h[13] = __expf(dvt*An[13])*h[13] + dvx*B3.y;
    h[14] = __expf(dvt*An[14])*h[14] + dvx*B3.z;
    h[15] = __expf(dvt*An[15])*h[15] + dvx*B3.w;
  }
  size_t hbase = (((size_t)(b * NCHUNK + c) * D_INNER) + d) * 16;
  #pragma unroll
  for (int q = 0; q < 4; ++q) {
    float4 o = {h[q*4+0], h[q*4+1], h[q*4+2], h[q*4+3]};
    *(float4*)&Hbuf[hbase + q*4] = o;
  }
  Sbuf[((size_t)b * NCHUNK + c) * D_INNER + d] = Ssum;

  // ---- last-block-done: fused phase2 for this (b, 256-d column) ----
  __threadfence();
  __syncthreads();
  if (tid == 0)
    lastFlag = (atomicAdd(&cnt[b * 8 + blockIdx.x], 1) == NCHUNK - 1) ? 1 : 0;
  __syncthreads();
  if (!lastFlag) return;
  __threadfence();   // acquire: other blocks' Hbuf/Sbuf stores now visible

  const int n2  = tid & 15;
  const int dl2 = tid >> 4;            // 0..15
  float hr[16], An2[16];
  #pragma unroll
  for (int q = 0; q < 16; ++q) {
    int dq = blockIdx.x * 256 + dl2 + q * 16;
    An2[q] = -__expf(alog[dq * 16 + n2]);
    hr[q] = 0.f;
  }
  for (int c2 = 0; c2 < NCHUNK; ++c2) {
    #pragma unroll
    for (int q = 0; q < 16; ++q) {
      int dq = blockIdx.x * 256 + dl2 + q * 16;
      size_t idx = (((size_t)(b * NCHUNK + c2) * D_INNER) + dq) * 16 + n2;
      float hend = Hbuf[idx];
      float P = __expf(An2[q] * Sbuf[((size_t)b * NCHUNK + c2) * D_INNER + dq]);
      Hbuf[idx] = hr[q];               // h at chunk START
      hr[q] = P * hr[q] + hend;
    }
  }
}

__global__ __launch_bounds__(256) void scan_phase3(
    const unsigned short* __restrict__ xsbf, const unsigned short* __restrict__ xar,
    const float* __restrict__ dlt, const float* __restrict__ Bmat,
    const float* __restrict__ Cmat, const float* __restrict__ dtw,
    const float* __restrict__ dtb, const float* __restrict__ alog,
    const float* __restrict__ Dvec, const float* __restrict__ Hbuf,
    unsigned short* __restrict__ ybf) {
  __shared__ float dltS[CHUNK][16];
  __shared__ float BS[CHUNK][16];
  __shared__ float CS[CHUNK][16];
  const int tid = threadIdx.x;
  const int c   = blockIdx.y;
  const int b   = blockIdx.z;
  const int d   = blockIdx.x * 256 + tid;
  const int row0 = b * SEQ + c * CHUNK;
  const __bf16* xsb16 = (const __bf16*)xsbf;
  const __bf16* xarb  = (const __bf16*)xar;
  {
    int e = tid * 2;
    int tt = e >> 4, r = e & 15;
    *(float2*)&dltS[tt][r] = *(const float2*)&dlt[(row0 + tt) * 16 + r];
    *(float2*)&BS[tt][r]   = *(const float2*)&Bmat[(row0 + tt) * 16 + r];
    *(float2*)&CS[tt][r]   = *(const float2*)&Cmat[(row0 + tt) * 16 + r];
  }
  float dtwr[16], An[16];
  #pragma unroll
  for (int q = 0; q < 4; ++q) {
    float4 w4 = *(const float4*)&dtw[d * 16 + q * 4];
    dtwr[q*4+0] = w4.x; dtwr[q*4+1] = w4.y; dtwr[q*4+2] = w4.z; dtwr[q*4+3] = w4.w;
    float4 a4 = *(const float4*)&alog[d * 16 + q * 4];
    An[q*4+0] = -__expf(a4.x); An[q*4+1] = -__expf(a4.y);
    An[q*4+2] = -__expf(a4.z); An[q*4+3] = -__expf(a4.w);
  }
  const float dtbv = dtb[d];
  const float Dn   = Dvec[d];
  float h[16];
  {
    size_t hbase = (((size_t)(b * NCHUNK + c) * D_INNER) + d) * 16;
    #pragma unroll
    for (int q = 0; q < 4; ++q) {
      float4 hv = *(const float4*)&Hbuf[hbase + q*4];
      h[q*4+0] = hv.x; h[q*4+1] = hv.y; h[q*4+2] = hv.z; h[q*4+3] = hv.w;
    }
  }
  float xv[CHUNK], rv[CHUNK];
  #pragma unroll
  for (int tt = 0; tt < CHUNK; ++tt) {
    xv[tt] = (float)xsb16[(size_t)(row0 + tt) * D_INNER + d];
    rv[tt] = (float)xarb[(size_t)(row0 + tt) * (2 * D_INNER) + D_INNER + d];
  }
  __syncthreads();
  float dv[CHUNK];
  #pragma unroll
  for (int tt = 0; tt < CHUNK; ++tt) {
    float s = dtbv;
    DELTA16(dltS, tt);
    dv[tt] = softplus_f(s);
  }
  #pragma unroll
  for (int tt = 0; tt < CHUNK; ++tt) {
    const float dvt = dv[tt];
    const float dvx = dvt * xv[tt];
    float4 B0 = *(const float4*)&BS[tt][0];
    float4 B1 = *(const float4*)&BS[tt][4];
    float4 B2 = *(const float4*)&BS[tt][8];
    float4 B3 = *(const float4*)&BS[tt][12];
    float4 C0 = *(const float4*)&CS[tt][0];
    float4 C1 = *(const float4*)&CS[tt][4];
    float4 C2 = *(const float4*)&CS[tt][8];
    float4 C3 = *(const float4*)&CS[tt][12];
    float y = 0.f;
    h[0]  = __expf(dvt*An[0])*h[0]   + dvx*B0.x;  y += h[0]*C0.x;
    h[1]  = __expf(dvt*An[1])*h[1]   + dvx*B0.y;  y += h[1]*C0.y;
    h[2]  = __expf(dvt*An[2])*h[2]   + dvx*B0.z;  y += h[2]*C0.z;
    h[3]  = __expf(dvt*An[3])*h[3]   + dvx*B0.w;  y += h[3]*C0.w;
    h[4]  = __expf(dvt*An[4])*h[4]   + dvx*B1.x;  y += h[4]*C1.x;
    h[5]  = __expf(dvt*An[5])*h[5]   + dvx*B1.y;  y += h[5]*C1.y;
    h[6]  = __expf(dvt*An[6])*h[6]   + dvx*B1.z;  y += h[6]*C1.z;
    h[7]  = __expf(dvt*An[7])*h[7]   + dvx*B1.w;  y += h[7]*C1.w;
    h[8]  = __expf(dvt*An[8])*h[8]   + dvx*B2.x;  y += h[8]*C2.x;
    h[9]  = __expf(dvt*An[9])*h[9]   + dvx*B2.y;  y += h[9]*C2.y;
    h[10] = __expf(dvt*An[10])*h[10] + dvx*B2.z;  y += h[10]*C2.z;
    h[11] = __expf(dvt*An[11])*h[11] + dvx*B2.w;  y += h[11]*C2.w;
    h[12] = __expf(dvt*An[12])*h[12] + dvx*B3.x;  y += h[12]*C3.x;
    h[13] = __expf(dvt*An[13])*h[13] + dvx*B3.y;  y += h[13]*C3.y;
    h[14] = __expf(dvt*An[14])*h[14] + dvx*B3.z;  y += h[14]*C3.z;
    h[15] = __expf(dvt*An[15])*h[15] + dvx*B3.w;  y += h[15]*C3.w;
    y += xv[tt] * Dn;
    const float r = rv[tt];
    const float v = y * (r * sigmoid_fast(r));
    ybf[(size_t)(row0 + tt) * D_INNER + d] = f2bf(v);
  }
}

// ---------------- launcher ----------------
extern "C" void kernel_launch(void* const* d_in, const int* in_sizes, int n_in,
                              void* d_out, int out_size, void* d_ws, size_t ws_size,
                              hipStream_t stream) {
  const float* x    = (const float*)d_in[0];
  const float* ipw  = (const float*)d_in[1];
  const float* ipb  = (const float*)d_in[2];
  const float* cw   = (const float*)d_in[3];
  const float* cb   = (const float*)d_in[4];
  const float* xpw  = (const float*)d_in[5];
  const float* xpb  = (const float*)d_in[6];
  const float* dtw  = (const float*)d_in[7];
  const float* dtb  = (const float*)d_in[8];
  const float* alog = (const float*)d_in[9];
  const float* Dv   = (const float*)d_in[10];
  const float* opw  = (const float*)d_in[11];
  const float* opb  = (const float*)d_in[12];
  float* out = (float*)d_out;

  char* ws = (char*)d_ws;
  size_t off = 0;
  auto alloc = [&](size_t bytes) {
    char* p = ws + off;
    off += (bytes + 255) & ~(size_t)255;
    return p;
  };
  unsigned short* xbf   = (unsigned short*)alloc((size_t)M_ROWS * D_MODEL * 2);       // 4 MB
  unsigned short* w1bf  = (unsigned short*)alloc((size_t)2 * D_INNER * D_MODEL * 2);  // 8 MB
  unsigned short* w2bf  = (unsigned short*)alloc((size_t)D_MODEL * D_INNER * 2);      // 4 MB
  unsigned short* xpwbf = (unsigned short*)alloc((size_t)48 * D_INNER * 2);           // 192 KB
  unsigned short* xar   = (unsigned short*)alloc((size_t)M_ROWS * 2 * D_INNER * 2);   // 16 MB bf16
  unsigned short* xsbf  = (unsigned short*)alloc((size_t)M_ROWS * D_INNER * 2);       // 8 MB
  float* dlt = (float*)alloc((size_t)M_ROWS * 16 * 4);   // 128 KB } contiguous,
  float* Bm  = (float*)alloc((size_t)M_ROWS * 16 * 4);   // 128 KB } zeroed by
  float* Cm  = (float*)alloc((size_t)M_ROWS * 16 * 4);   // 128 KB } cast_all
  int*   cnt = (int*)alloc(256);                         // 16 counters (zeroed too)
  unsigned short* ybf = (unsigned short*)alloc((size_t)M_ROWS * D_INNER * 2);         // 8 MB
  if (off > ws_size) return;
  // w1bf region (8 MB) is dead after gemm1; reused for Hbuf (phase1 -> phase3).
  float* Hbuf = (float*)w1bf;   // [B][NCHUNK][D_INNER][16] f32 = 8 MB exactly
  float* Sbuf = (float*)xbf;    // xbf dead after gemm1; Sbuf = 512 KB

  // 1. casts + zero dlt/Bm/Cm/cnt. elements = 2146320 -> grid 8385 (guarded tail)
  cast_all_kernel<<<8385, 256, 0, stream>>>(x, ipw, opw, xpw, xbf, w1bf, w2bf, xpwbf, dlt);
  // 2. in_proj -> bf16 xar; BK=64
  gemm_gll<128, 64, unsigned short><<<dim3(4096 / 128, 2048 / 128), 256, 0, stream>>>(
      (const __bf16*)xbf, (const __bf16*)w1bf, ipb, xar, M_ROWS, 2 * D_INNER, D_MODEL);
  // 3. FUSED conv+silu+x_proj: grid (32 rowtiles, 16 ksplits)
  convxproj_kernel<<<dim3(M_ROWS / 64, XP_KSPLIT), 256, 0, stream>>>(
      xar, cw, cb, (const __bf16*)xpwbf, xpb, xsbf, dlt, Bm, Cm);
  // 4. scan phase1 (+fused phase2 tail via last-block-done)
  scan_phase1<<<dim3(D_INNER / 256, NCHUNK, BATCH), 256, 0, stream>>>(
      xsbf, dlt, Bm, dtw, dtb, alog, Hbuf, Sbuf, cnt);
  // 5. scan phase3
  scan_phase3<<<dim3(D_INNER / 256, NCHUNK, BATCH), 256, 0, stream>>>(
      xsbf, xar, dlt, Bm, Cm, dtw, dtb, alog, Dv, Hbuf, ybf);
  // 6. out_proj: 64x128 tiles, BK=64, 256 wgs, f32 out
  gemm_gll<64, 64, float><<<dim3(1024 / 128, 2048 / 64), 256, 0, stream>>>(
      (const __bf16*)ybf, (const __bf16*)w2bf, opb, out, M_ROWS, D_MODEL, D_INNER);
}